// Round 3
// baseline (1254.168 us; speedup 1.0000x reference)
//
#include <hip/hip_runtime.h>
#include <math.h>

// Problem constants: B=4, CG=384, CY=2, H=W=224, CH=32
#define HW2 50176            // 224*224
#define NPLANE 6422528       // 4*32*224*224  (one [B,32,H,W] tensor)

typedef float f4 __attribute__((ext_vector_type(4)));  // native vec for nt-load/store

// ---------------------------------------------------------------------------
// conv_end_3: [4,2,224,224] -> [4,32,224,224], 3x3 same, no bias
// ---------------------------------------------------------------------------
__global__ __launch_bounds__(256) void conv3_kernel(const float* __restrict__ y,
                                                    const float* __restrict__ w3,
                                                    float* __restrict__ y32)
{
    int idx = blockIdx.x * 256 + threadIdx.x;
    if (idx >= NPLANE) return;
    int w  = idx % 224;
    int h  = (idx / 224) % 224;
    int co = (idx / HW2) % 32;
    int b  = idx / (HW2 * 32);
    const float* yb = y + (size_t)b * 2 * HW2;
    float acc = 0.f;
#pragma unroll
    for (int ci = 0; ci < 2; ci++) {
#pragma unroll
        for (int kh = 0; kh < 3; kh++) {
            int hy = h + kh - 1;
            if (hy < 0 || hy > 223) continue;
#pragma unroll
            for (int kw = 0; kw < 3; kw++) {
                int wy = w + kw - 1;
                if (wy < 0 || wy > 223) continue;
                acc += yb[ci * HW2 + hy * 224 + wy] * w3[((co * 2 + ci) * 3 + kh) * 3 + kw];
            }
        }
    }
    y32[idx] = acc;
}

// ---------------------------------------------------------------------------
// Gate step: h = (1-Σa)x + a1*hu + a2*hc + a3*hd, ai = gi/max(Σ|gi|,1)
//          = x + (g1*(hu-x) + g2*(hc-x) + g3*(hd-x)) * rcp(den)
// ---------------------------------------------------------------------------
__device__ __forceinline__ float gstep(float a1, float a2, float a3, float xv,
                                       float hu, float hc, float hd)
{
    float den = fmaxf(fabsf(a1) + fabsf(a2) + fabsf(a3), 1.0f);
    float r = __builtin_amdgcn_rcpf(den);   // den >= 1, ~1ulp rel err, fine vs 7.8e-2 thr
    float t = a1 * (hu - xv) + a2 * (hc - xv) + a3 * (hd - xv);
    return fmaf(t, r, xv);
}

// ===========================================================================
// Wave-per-plane scans: ONE 64-lane wave owns one (dir,b,ch) plane.
// Lane l holds 4 h-values (s = 4l..4l+3, active for l<56; lanes 56-63 carry
// h=0 via zeroed inputs). Neighbor coupling = 2 shuffles, NO barriers, so
// register prefetch of the next 4-step chunk stays in flight across steps.
// ===========================================================================

// ---- vertical scan (steps over rows H, coupling along W) -------------------
// lane covers 4 consecutive COLUMNS; per step loads are wave-coalesced rows.
template <bool REV>
__device__ __forceinline__ void vload(f4& d1, f4& d2, f4& d3, f4 dx[1],
                                      const float* __restrict__ g1, const float* __restrict__ g2,
                                      const float* __restrict__ g3, const float* __restrict__ xp,
                                      int i, int col, bool act)
{
    int r = REV ? 223 - i : i;
    int off = r * 224 + col;
    if (act) {
        d1 = __builtin_nontemporal_load((const f4*)&g1[off]);
        d2 = __builtin_nontemporal_load((const f4*)&g2[off]);
        d3 = __builtin_nontemporal_load((const f4*)&g3[off]);
        dx[0] = *(const f4*)&xp[off];
    } else {
        d1 = (f4)0.f; d2 = (f4)0.f; d3 = (f4)0.f; dx[0] = (f4)0.f;
    }
}

template <bool REV>
__device__ __forceinline__ void vload4(f4 d1[4], f4 d2[4], f4 d3[4], f4 dx[4],
                                       const float* __restrict__ g1, const float* __restrict__ g2,
                                       const float* __restrict__ g3, const float* __restrict__ xp,
                                       int cc, int col, bool act)
{
#pragma unroll
    for (int j = 0; j < 4; j++)
        vload<REV>(d1[j], d2[j], d3[j], &dx[j], g1, g2, g3, xp, 4 * cc + j, col, act);
}

template <bool REV>
__device__ __forceinline__ void vcomp(const f4 b1[4], const f4 b2[4],
                                      const f4 b3[4], const f4 bx[4],
                                      float& h0, float& h1, float& h2, float& h3,
                                      float* __restrict__ op, int cc, int col,
                                      bool act, int lane)
{
#pragma unroll
    for (int j = 0; j < 4; j++) {
        float up = __shfl_up(h3, 1);
        if (lane == 0) up = 0.f;
        float dn = __shfl_down(h0, 1);       // lane>=56 h==0, so lane55 gets 0
        float t0 = gstep(b1[j].x, b2[j].x, b3[j].x, bx[j].x, up, h0, h1);
        float t1 = gstep(b1[j].y, b2[j].y, b3[j].y, bx[j].y, h0, h1, h2);
        float t2 = gstep(b1[j].z, b2[j].z, b3[j].z, bx[j].z, h1, h2, h3);
        float t3 = gstep(b1[j].w, b2[j].w, b3[j].w, bx[j].w, h2, h3, dn);
        h0 = t0; h1 = t1; h2 = t2; h3 = t3;
        if (act) {
            int i = 4 * cc + j;
            int r = REV ? 223 - i : i;
            f4 o; o.x = h0; o.y = h1; o.z = h2; o.w = h3;
            *(f4*)&op[r * 224 + col] = o;
        }
    }
}

template <bool REV>
__device__ void scan_v(const float* __restrict__ g1, const float* __restrict__ g2,
                       const float* __restrict__ g3, const float* __restrict__ xp,
                       float* __restrict__ op, int lane)
{
    const bool act = lane < 56;
    const int col = 4 * lane;
    float h0 = 0.f, h1 = 0.f, h2 = 0.f, h3 = 0.f;
    f4 A1[4], A2[4], A3[4], Ax[4];
    f4 B1[4], B2[4], B3[4], Bx[4];

    vload4<REV>(A1, A2, A3, Ax, g1, g2, g3, xp, 0, col, act);
#pragma unroll 1
    for (int cc = 0; cc < 56; cc += 2) {
        vload4<REV>(B1, B2, B3, Bx, g1, g2, g3, xp, cc + 1, col, act);
        vcomp<REV>(A1, A2, A3, Ax, h0, h1, h2, h3, op, cc, col, act, lane);
        if (cc + 2 < 56)
            vload4<REV>(A1, A2, A3, Ax, g1, g2, g3, xp, cc + 2, col, act);
        vcomp<REV>(B1, B2, B3, Bx, h0, h1, h2, h3, op, cc + 1, col, act, lane);
    }
}

// ---- horizontal scan (steps over cols W, coupling along H) -----------------
// lane covers 4 consecutive ROWS; loads stream each row in line-aligned
// float4 chunks (4 columns = 4 steps per chunk).
template <bool REV>
__device__ __forceinline__ void hload(f4 d1[4], f4 d2[4], f4 d3[4], f4 dx[4],
                                      const float* __restrict__ g1, const float* __restrict__ g2,
                                      const float* __restrict__ g3, const float* __restrict__ xp,
                                      int cc, int r0, bool act)
{
    int w0 = REV ? 220 - 4 * cc : 4 * cc;
#pragma unroll
    for (int rr = 0; rr < 4; rr++) {
        int off = (r0 + rr) * 224 + w0;
        if (act) {
            d1[rr] = __builtin_nontemporal_load((const f4*)&g1[off]);
            d2[rr] = __builtin_nontemporal_load((const f4*)&g2[off]);
            d3[rr] = __builtin_nontemporal_load((const f4*)&g3[off]);
            dx[rr] = *(const f4*)&xp[off];
        } else {
            d1[rr] = (f4)0.f; d2[rr] = (f4)0.f; d3[rr] = (f4)0.f; dx[rr] = (f4)0.f;
        }
    }
}

template <bool REV>
__device__ __forceinline__ void hcomp(const f4 b1[4], const f4 b2[4],
                                      const f4 b3[4], const f4 bx[4],
                                      float& h0, float& h1, float& h2, float& h3,
                                      float* __restrict__ op, int cc, int r0,
                                      bool act, int lane)
{
    f4 o[4];
#pragma unroll
    for (int j = 0; j < 4; j++) {
        const int e = REV ? 3 - j : j;      // element within the float4 chunk
        float up = __shfl_up(h3, 1);
        if (lane == 0) up = 0.f;
        float dn = __shfl_down(h0, 1);
        float t0 = gstep(b1[0][e], b2[0][e], b3[0][e], bx[0][e], up, h0, h1);
        float t1 = gstep(b1[1][e], b2[1][e], b3[1][e], bx[1][e], h0, h1, h2);
        float t2 = gstep(b1[2][e], b2[2][e], b3[2][e], bx[2][e], h1, h2, h3);
        float t3 = gstep(b1[3][e], b2[3][e], b3[3][e], bx[3][e], h2, h3, dn);
        h0 = t0; h1 = t1; h2 = t2; h3 = t3;
        o[0][e] = t0; o[1][e] = t1; o[2][e] = t2; o[3][e] = t3;
    }
    if (act) {
        int w0 = REV ? 220 - 4 * cc : 4 * cc;
#pragma unroll
        for (int rr = 0; rr < 4; rr++)
            *(f4*)&op[(r0 + rr) * 224 + w0] = o[rr];
    }
}

template <bool REV>
__device__ void scan_h(const float* __restrict__ g1, const float* __restrict__ g2,
                       const float* __restrict__ g3, const float* __restrict__ xp,
                       float* __restrict__ op, int lane)
{
    const bool act = lane < 56;
    const int r0 = 4 * lane;
    float h0 = 0.f, h1 = 0.f, h2 = 0.f, h3 = 0.f;
    f4 A1[4], A2[4], A3[4], Ax[4];
    f4 B1[4], B2[4], B3[4], Bx[4];

    hload<REV>(A1, A2, A3, Ax, g1, g2, g3, xp, 0, r0, act);
#pragma unroll 1
    for (int cc = 0; cc < 56; cc += 2) {
        hload<REV>(B1, B2, B3, Bx, g1, g2, g3, xp, cc + 1, r0, act);
        hcomp<REV>(A1, A2, A3, Ax, h0, h1, h2, h3, op, cc, r0, act, lane);
        if (cc + 2 < 56)
            hload<REV>(A1, A2, A3, Ax, g1, g2, g3, xp, cc + 2, r0, act);
        hcomp<REV>(B1, B2, B3, Bx, h0, h1, h2, h3, op, cc + 1, r0, act, lane);
    }
}

// One block = one wave = one (dir,b,ch) plane. 512 blocks x 64 threads.
// Adjacent blocks = 4 directions of the same (b,c) so x reads share L2/L3.
// d0: horiz fwd (ylr); d1: vert rev (yrl); d2: vert fwd (ydu); d3: horiz rev (yud)
__global__ __launch_bounds__(64) void scan_kernel(const float* __restrict__ gates,
                                                  const float* __restrict__ x,
                                                  float* __restrict__ D)
{
    int bid = blockIdx.x;
    int d = bid & 3;
    int p = bid >> 2;           // 0..127
    int b = p >> 5;
    int c = p & 31;
    int lane = threadIdx.x;

    const float* g1 = gates + (size_t)(b * 384 + 3 * d * 32 + c) * HW2;
    const float* g2 = g1 + 32 * (size_t)HW2;
    const float* g3 = g2 + 32 * (size_t)HW2;
    const float* xp = x + (size_t)(b * 32 + c) * HW2;
    float* op = D + (size_t)d * NPLANE + (size_t)(b * 32 + c) * HW2;

    if (d == 0)      scan_h<false>(g1, g2, g3, xp, op, lane);
    else if (d == 1) scan_v<true >(g1, g2, g3, xp, op, lane);
    else if (d == 2) scan_v<false>(g1, g2, g3, xp, op, lane);
    else             scan_h<true >(g1, g2, g3, xp, op, lane);
}

// ---------------------------------------------------------------------------
// Elementwise max over the 4 direction buffers
// ---------------------------------------------------------------------------
__global__ __launch_bounds__(256) void max4_kernel(const float* __restrict__ D,
                                                   float* __restrict__ o)
{
    const int NP4 = NPLANE / 4;
    int idx = blockIdx.x * 256 + threadIdx.x;
    if (idx >= NP4) return;
    const f4* d0 = (const f4*)D;
    const f4* d1 = d0 + NP4;
    const f4* d2 = d1 + NP4;
    const f4* d3 = d2 + NP4;
    f4 a = d0[idx], b = d1[idx], c = d2[idx], d = d3[idx];
    f4 r;
    r.x = fmaxf(fmaxf(a.x, b.x), fmaxf(c.x, d.x));
    r.y = fmaxf(fmaxf(a.y, b.y), fmaxf(c.y, d.y));
    r.z = fmaxf(fmaxf(a.z, b.z), fmaxf(c.z, d.z));
    r.w = fmaxf(fmaxf(a.w, b.w), fmaxf(c.w, d.w));
    ((f4*)o)[idx] = r;
}

// ---------------------------------------------------------------------------
// conv_end_4 (32->2, 3x3 same) fused with log_softmax over the 2 channels
// ---------------------------------------------------------------------------
__global__ __launch_bounds__(256) void conv4ls_kernel(const float* __restrict__ x,
                                                      const float* __restrict__ w4,
                                                      float* __restrict__ out)
{
    __shared__ float wsh[576];
    for (int i = threadIdx.x; i < 576; i += 256) wsh[i] = w4[i];
    __syncthreads();
    int idx = blockIdx.x * 256 + threadIdx.x;
    if (idx >= 4 * HW2) return;
    int w = idx % 224;
    int h = (idx / 224) % 224;
    int b = idx / HW2;
    const float* xb = x + (size_t)b * 32 * HW2;
    float acc0 = 0.f, acc1 = 0.f;
    for (int ci = 0; ci < 32; ci++) {
        const float* xc = xb + ci * HW2;
#pragma unroll
        for (int kh = 0; kh < 3; kh++) {
            int hy = h + kh - 1;
            if (hy < 0 || hy > 223) continue;
#pragma unroll
            for (int kw = 0; kw < 3; kw++) {
                int wy = w + kw - 1;
                if (wy < 0 || wy > 223) continue;
                float v = xc[hy * 224 + wy];
                acc0 += v * wsh[(ci * 3 + kh) * 3 + kw];
                acc1 += v * wsh[288 + (ci * 3 + kh) * 3 + kw];
            }
        }
    }
    float m = fmaxf(acc0, acc1);
    float l = m + logf(expf(acc0 - m) + expf(acc1 - m));
    out[(size_t)(b * 2) * HW2 + h * 224 + w]     = acc0 - l;
    out[(size_t)(b * 2 + 1) * HW2 + h * 224 + w] = acc1 - l;
}

// ---------------------------------------------------------------------------
extern "C" void kernel_launch(void* const* d_in, const int* in_sizes, int n_in,
                              void* d_out, int out_size, void* d_ws, size_t ws_size,
                              hipStream_t stream)
{
    const float* gates = (const float*)d_in[0];  // [4,384,224,224]
    const float* y     = (const float*)d_in[1];  // [4,2,224,224]
    const float* w3    = (const float*)d_in[2];  // [32,2,3,3]
    const float* w4    = (const float*)d_in[3];  // [2,32,3,3]
    float* out = (float*)d_out;                  // [4,2,224,224]
    float* ws  = (float*)d_ws;

    float* y32 = ws;                 // NPLANE floats; reused as y1 / max buffer
    float* D   = ws + NPLANE;        // 4 * NPLANE floats (direction outputs)

    conv3_kernel<<<NPLANE / 256, 256, 0, stream>>>(y, w3, y32);
    scan_kernel<<<512, 64, 0, stream>>>(gates, y32, D);
    max4_kernel<<<NPLANE / 4 / 256, 256, 0, stream>>>(D, y32);
    scan_kernel<<<512, 64, 0, stream>>>(gates, y32, D);
    max4_kernel<<<NPLANE / 4 / 256, 256, 0, stream>>>(D, y32);
    conv4ls_kernel<<<(4 * HW2) / 256, 256, 0, stream>>>(y32, w4, out);
}

// Round 4
// 830.285 us; speedup vs baseline: 1.5105x; 1.5105x over previous
//
#include <hip/hip_runtime.h>
#include <math.h>

// Problem constants: B=4, CG=384, CY=2, H=W=224, CH=32
#define HW2 50176            // 224*224
#define NPLANE 6422528       // 4*32*224*224  (one [B,32,H,W] tensor)

typedef float f4 __attribute__((ext_vector_type(4)));
typedef _Float16 h4 __attribute__((ext_vector_type(4)));

// ws layout (packed path): [x: NPLANE f32][D: 4*NPLANE f32][GT: 6*128*HW2 fp16]
#define WS_NEED (( (size_t)NPLANE * 5 * 4 ) + ( (size_t)6 * 128 * HW2 * 2 ))

// ---------------------------------------------------------------------------
// conv_end_3: [4,2,224,224] -> [4,32,224,224], 3x3 same, no bias
// ---------------------------------------------------------------------------
__global__ __launch_bounds__(256) void conv3_kernel(const float* __restrict__ y,
                                                    const float* __restrict__ w3,
                                                    float* __restrict__ y32)
{
    int idx = blockIdx.x * 256 + threadIdx.x;
    if (idx >= NPLANE) return;
    int w  = idx % 224;
    int h  = (idx / 224) % 224;
    int co = (idx / HW2) % 32;
    int b  = idx / (HW2 * 32);
    const float* yb = y + (size_t)b * 2 * HW2;
    float acc = 0.f;
#pragma unroll
    for (int ci = 0; ci < 2; ci++) {
#pragma unroll
        for (int kh = 0; kh < 3; kh++) {
            int hy = h + kh - 1;
            if (hy < 0 || hy > 223) continue;
#pragma unroll
            for (int kw = 0; kw < 3; kw++) {
                int wy = w + kw - 1;
                if (wy < 0 || wy > 223) continue;
                acc += yb[ci * HW2 + hy * 224 + wy] * w3[((co * 2 + ci) * 3 + kh) * 3 + kw];
            }
        }
    }
    y32[idx] = acc;
}

// ---------------------------------------------------------------------------
// packT: transpose the 6 horizontal gate planes (g0,g1,g2,g9,g10,g11) per
// (b,c) into [w][h] fp16.  32x32 LDS tiles, block (32,8).
// GT slot s in 0..5 -> gate index gi = s<3 ? s : 6+s.
// ---------------------------------------------------------------------------
__global__ __launch_bounds__(256) void packT_kernel(const float* __restrict__ gates,
                                                    _Float16* __restrict__ GT)
{
    int bid = blockIdx.x;
    int tile = bid % 49;
    int pc = bid / 49;          // s*128 + b*32 + c
    int s = pc >> 7;
    int b = (pc >> 5) & 3;
    int c = pc & 31;
    int gi = s < 3 ? s : 6 + s;
    int h0 = (tile % 7) * 32, w0 = (tile / 7) * 32;
    const float* in = gates + (size_t)(b * 384 + gi * 32 + c) * HW2;
    _Float16* out = GT + (size_t)pc * HW2;
    __shared__ float t[32][33];
    int tx = threadIdx.x, ty = threadIdx.y;
#pragma unroll
    for (int k = 0; k < 4; k++)
        t[ty + 8 * k][tx] = in[(h0 + ty + 8 * k) * 224 + w0 + tx];
    __syncthreads();
#pragma unroll
    for (int k = 0; k < 4; k++)
        out[(w0 + ty + 8 * k) * 224 + h0 + tx] = (_Float16)t[tx][ty + 8 * k];
}

// ---------------------------------------------------------------------------
// Gate step: h = x + (g1*(hu-x) + g2*(hc-x) + g3*(hd-x)) * rcp(max(sum|g|,1))
// ---------------------------------------------------------------------------
__device__ __forceinline__ float gstep(float a1, float a2, float a3, float xv,
                                       float hu, float hc, float hd)
{
    float den = fmaxf(fabsf(a1) + fabsf(a2) + fabsf(a3), 1.0f);
    float r = __builtin_amdgcn_rcpf(den);
    float t = a1 * (hu - xv) + a2 * (hc - xv) + a3 * (hd - xv);
    return fmaf(t, r, xv);
}

// ===========================================================================
// Wave-per-plane scans. Lane l owns 4 in-row elements (l<56 active).
// Neighbor coupling = 2 shuffles, barrier-free; 2-chunk register prefetch.
// ===========================================================================

// ---- fp32 vertical scan (d1,d2): steps over rows, full-row coalesced -------
template <bool REV>
__device__ __forceinline__ void vload4(f4 d1[4], f4 d2[4], f4 d3[4], f4 dx[4],
                                       const float* __restrict__ g1, const float* __restrict__ g2,
                                       const float* __restrict__ g3, const float* __restrict__ xp,
                                       int cc, int col, bool act)
{
#pragma unroll
    for (int j = 0; j < 4; j++) {
        int i = 4 * cc + j;
        int r = REV ? 223 - i : i;
        int off = r * 224 + col;
        if (act) {
            d1[j] = __builtin_nontemporal_load((const f4*)&g1[off]);
            d2[j] = __builtin_nontemporal_load((const f4*)&g2[off]);
            d3[j] = __builtin_nontemporal_load((const f4*)&g3[off]);
            dx[j] = *(const f4*)&xp[off];
        } else {
            d1[j] = (f4)0.f; d2[j] = (f4)0.f; d3[j] = (f4)0.f; dx[j] = (f4)0.f;
        }
    }
}

template <bool REV>
__device__ __forceinline__ void vcomp(const f4 b1[4], const f4 b2[4],
                                      const f4 b3[4], const f4 bx[4],
                                      float& h0, float& h1, float& h2, float& h3,
                                      float* __restrict__ op, int cc, int col,
                                      bool act, int lane)
{
#pragma unroll
    for (int j = 0; j < 4; j++) {
        float up = __shfl_up(h3, 1);
        if (lane == 0) up = 0.f;
        float dn = __shfl_down(h0, 1);
        float t0 = gstep(b1[j].x, b2[j].x, b3[j].x, bx[j].x, up, h0, h1);
        float t1 = gstep(b1[j].y, b2[j].y, b3[j].y, bx[j].y, h0, h1, h2);
        float t2 = gstep(b1[j].z, b2[j].z, b3[j].z, bx[j].z, h1, h2, h3);
        float t3 = gstep(b1[j].w, b2[j].w, b3[j].w, bx[j].w, h2, h3, dn);
        h0 = t0; h1 = t1; h2 = t2; h3 = t3;
        if (act) {
            int i = 4 * cc + j;
            int r = REV ? 223 - i : i;
            f4 o; o.x = h0; o.y = h1; o.z = h2; o.w = h3;
            *(f4*)&op[r * 224 + col] = o;
        }
    }
}

template <bool REV>
__device__ void scan_v(const float* __restrict__ g1, const float* __restrict__ g2,
                       const float* __restrict__ g3, const float* __restrict__ xp,
                       float* __restrict__ op, int lane)
{
    const bool act = lane < 56;
    const int col = 4 * lane;
    float h0 = 0.f, h1 = 0.f, h2 = 0.f, h3 = 0.f;
    f4 A1[4], A2[4], A3[4], Ax[4];
    f4 B1[4], B2[4], B3[4], Bx[4];

    vload4<REV>(A1, A2, A3, Ax, g1, g2, g3, xp, 0, col, act);
#pragma unroll 1
    for (int cc = 0; cc < 56; cc += 2) {
        vload4<REV>(B1, B2, B3, Bx, g1, g2, g3, xp, cc + 1, col, act);
        vcomp<REV>(A1, A2, A3, Ax, h0, h1, h2, h3, op, cc, col, act, lane);
        if (cc + 2 < 56)
            vload4<REV>(A1, A2, A3, Ax, g1, g2, g3, xp, cc + 2, col, act);
        vcomp<REV>(B1, B2, B3, Bx, h0, h1, h2, h3, op, cc + 1, col, act, lane);
    }
}

// ---- fp16 transposed scan (d0,d3): gates from GT [w][h] rows (coalesced),
// x read column-strided (25.7 MB, L2/L3-resident), output transposed --------
template <bool REV>
__device__ __forceinline__ void tload4(h4 d1[4], h4 d2[4], h4 d3[4], f4 dx[4],
                                       const _Float16* __restrict__ g1, const _Float16* __restrict__ g2,
                                       const _Float16* __restrict__ g3, const float* __restrict__ xp,
                                       int cc, int col, bool act)
{
#pragma unroll
    for (int j = 0; j < 4; j++) {
        int i = 4 * cc + j;
        int r = REV ? 223 - i : i;
        int off = r * 224 + col;
        if (act) {
            d1[j] = *(const h4*)&g1[off];
            d2[j] = *(const h4*)&g2[off];
            d3[j] = *(const h4*)&g3[off];
            f4 xv;
            xv.x = xp[(col + 0) * 224 + r];
            xv.y = xp[(col + 1) * 224 + r];
            xv.z = xp[(col + 2) * 224 + r];
            xv.w = xp[(col + 3) * 224 + r];
            dx[j] = xv;
        } else {
            d1[j] = (h4)(_Float16)0; d2[j] = (h4)(_Float16)0; d3[j] = (h4)(_Float16)0;
            dx[j] = (f4)0.f;
        }
    }
}

template <bool REV>
__device__ __forceinline__ void tcomp(const h4 b1[4], const h4 b2[4],
                                      const h4 b3[4], const f4 bx[4],
                                      float& h0, float& h1, float& h2, float& h3,
                                      float* __restrict__ op, int cc, int col,
                                      bool act, int lane)
{
#pragma unroll
    for (int j = 0; j < 4; j++) {
        float up = __shfl_up(h3, 1);
        if (lane == 0) up = 0.f;
        float dn = __shfl_down(h0, 1);
        float t0 = gstep((float)b1[j].x, (float)b2[j].x, (float)b3[j].x, bx[j].x, up, h0, h1);
        float t1 = gstep((float)b1[j].y, (float)b2[j].y, (float)b3[j].y, bx[j].y, h0, h1, h2);
        float t2 = gstep((float)b1[j].z, (float)b2[j].z, (float)b3[j].z, bx[j].z, h1, h2, h3);
        float t3 = gstep((float)b1[j].w, (float)b2[j].w, (float)b3[j].w, bx[j].w, h2, h3, dn);
        h0 = t0; h1 = t1; h2 = t2; h3 = t3;
        if (act) {
            int i = 4 * cc + j;
            int r = REV ? 223 - i : i;
            f4 o; o.x = h0; o.y = h1; o.z = h2; o.w = h3;
            *(f4*)&op[r * 224 + col] = o;   // transposed layout [w][h]
        }
    }
}

template <bool REV>
__device__ void scan_t(const _Float16* __restrict__ g1, const _Float16* __restrict__ g2,
                       const _Float16* __restrict__ g3, const float* __restrict__ xp,
                       float* __restrict__ op, int lane)
{
    const bool act = lane < 56;
    const int col = 4 * lane;
    float h0 = 0.f, h1 = 0.f, h2 = 0.f, h3 = 0.f;
    h4 A1[4], A2[4], A3[4]; f4 Ax[4];
    h4 B1[4], B2[4], B3[4]; f4 Bx[4];

    tload4<REV>(A1, A2, A3, Ax, g1, g2, g3, xp, 0, col, act);
#pragma unroll 1
    for (int cc = 0; cc < 56; cc += 2) {
        tload4<REV>(B1, B2, B3, Bx, g1, g2, g3, xp, cc + 1, col, act);
        tcomp<REV>(A1, A2, A3, Ax, h0, h1, h2, h3, op, cc, col, act, lane);
        if (cc + 2 < 56)
            tload4<REV>(A1, A2, A3, Ax, g1, g2, g3, xp, cc + 2, col, act);
        tcomp<REV>(B1, B2, B3, Bx, h0, h1, h2, h3, op, cc + 1, col, act, lane);
    }
}

// Packed-path scan: d0/d3 via transposed fp16 gates; d1/d2 via fp32 gates.
// D planes d0,d3 stored transposed [w][h]; d1,d2 normal [h][w].
__global__ __launch_bounds__(64) void scanP_kernel(const float* __restrict__ gates,
                                                   const _Float16* __restrict__ GT,
                                                   const float* __restrict__ x,
                                                   float* __restrict__ D)
{
    int bid = blockIdx.x;
    int d = bid & 3;
    int p = bid >> 2;            // b*32 + c
    int b = p >> 5;
    int c = p & 31;
    int lane = threadIdx.x;

    const float* xp = x + (size_t)p * HW2;
    float* op = D + (size_t)d * NPLANE + (size_t)p * HW2;

    if (d == 1 || d == 2) {
        int gi = (d == 1) ? 3 : 6;
        const float* g1 = gates + (size_t)(b * 384 + gi * 32 + c) * HW2;
        const float* g2 = g1 + 32 * (size_t)HW2;
        const float* g3 = g2 + 32 * (size_t)HW2;
        if (d == 1) scan_v<true >(g1, g2, g3, xp, op, lane);
        else        scan_v<false>(g1, g2, g3, xp, op, lane);
    } else {
        int s = (d == 0) ? 0 : 3;
        const _Float16* g1 = GT + (size_t)(s * 128 + p) * HW2;
        const _Float16* g2 = g1 + 128 * (size_t)HW2;
        const _Float16* g3 = g2 + 128 * (size_t)HW2;
        if (d == 0) scan_t<false>(g1, g2, g3, xp, op, lane);
        else        scan_t<true >(g1, g2, g3, xp, op, lane);
    }
}

// ---------------------------------------------------------------------------
// max4T: merge d1,d2 (normal) + d0,d3 (transposed) -> normal layout.
// 32x32 LDS tiles, block (32,8), grid 128*49.
// ---------------------------------------------------------------------------
__global__ __launch_bounds__(256) void max4T_kernel(const float* __restrict__ D,
                                                    float* __restrict__ o)
{
    int bid = blockIdx.x;
    int tile = bid % 49;
    int p = bid / 49;
    int h0 = (tile % 7) * 32, w0 = (tile / 7) * 32;
    const float* d0 = D + (size_t)p * HW2;                         // transposed
    const float* d1 = D + (size_t)NPLANE + (size_t)p * HW2;
    const float* d2 = D + 2 * (size_t)NPLANE + (size_t)p * HW2;
    const float* d3 = D + 3 * (size_t)NPLANE + (size_t)p * HW2;    // transposed
    float* op = o + (size_t)p * HW2;
    __shared__ float ta[32][33], tb[32][33];
    int tx = threadIdx.x, ty = threadIdx.y;
#pragma unroll
    for (int k = 0; k < 4; k++) {
        int off = (w0 + ty + 8 * k) * 224 + h0 + tx;
        ta[ty + 8 * k][tx] = d0[off];
        tb[ty + 8 * k][tx] = d3[off];
    }
    __syncthreads();
#pragma unroll
    for (int k = 0; k < 4; k++) {
        int idx = (h0 + ty + 8 * k) * 224 + w0 + tx;
        float v = fmaxf(fmaxf(d1[idx], d2[idx]),
                        fmaxf(ta[tx][ty + 8 * k], tb[tx][ty + 8 * k]));
        op[idx] = v;
    }
}

// ===========================================================================
// Fallback path (ws too small): R3 scans, nt dropped on horizontal loads.
// ===========================================================================
template <bool REV>
__device__ __forceinline__ void hload(f4 d1[4], f4 d2[4], f4 d3[4], f4 dx[4],
                                      const float* __restrict__ g1, const float* __restrict__ g2,
                                      const float* __restrict__ g3, const float* __restrict__ xp,
                                      int cc, int r0, bool act)
{
    int w0 = REV ? 220 - 4 * cc : 4 * cc;
#pragma unroll
    for (int rr = 0; rr < 4; rr++) {
        int off = (r0 + rr) * 224 + w0;
        if (act) {
            d1[rr] = *(const f4*)&g1[off];
            d2[rr] = *(const f4*)&g2[off];
            d3[rr] = *(const f4*)&g3[off];
            dx[rr] = *(const f4*)&xp[off];
        } else {
            d1[rr] = (f4)0.f; d2[rr] = (f4)0.f; d3[rr] = (f4)0.f; dx[rr] = (f4)0.f;
        }
    }
}

template <bool REV>
__device__ __forceinline__ void hcomp(const f4 b1[4], const f4 b2[4],
                                      const f4 b3[4], const f4 bx[4],
                                      float& h0, float& h1, float& h2, float& h3,
                                      float* __restrict__ op, int cc, int r0,
                                      bool act, int lane)
{
    f4 o[4];
#pragma unroll
    for (int j = 0; j < 4; j++) {
        const int e = REV ? 3 - j : j;
        float up = __shfl_up(h3, 1);
        if (lane == 0) up = 0.f;
        float dn = __shfl_down(h0, 1);
        float t0 = gstep(b1[0][e], b2[0][e], b3[0][e], bx[0][e], up, h0, h1);
        float t1 = gstep(b1[1][e], b2[1][e], b3[1][e], bx[1][e], h0, h1, h2);
        float t2 = gstep(b1[2][e], b2[2][e], b3[2][e], bx[2][e], h1, h2, h3);
        float t3 = gstep(b1[3][e], b2[3][e], b3[3][e], bx[3][e], h2, h3, dn);
        h0 = t0; h1 = t1; h2 = t2; h3 = t3;
        o[0][e] = t0; o[1][e] = t1; o[2][e] = t2; o[3][e] = t3;
    }
    if (act) {
        int w0 = REV ? 220 - 4 * cc : 4 * cc;
#pragma unroll
        for (int rr = 0; rr < 4; rr++)
            *(f4*)&op[(r0 + rr) * 224 + w0] = o[rr];
    }
}

template <bool REV>
__device__ void scan_h(const float* __restrict__ g1, const float* __restrict__ g2,
                       const float* __restrict__ g3, const float* __restrict__ xp,
                       float* __restrict__ op, int lane)
{
    const bool act = lane < 56;
    const int r0 = 4 * lane;
    float h0 = 0.f, h1 = 0.f, h2 = 0.f, h3 = 0.f;
    f4 A1[4], A2[4], A3[4], Ax[4];
    f4 B1[4], B2[4], B3[4], Bx[4];

    hload<REV>(A1, A2, A3, Ax, g1, g2, g3, xp, 0, r0, act);
#pragma unroll 1
    for (int cc = 0; cc < 56; cc += 2) {
        hload<REV>(B1, B2, B3, Bx, g1, g2, g3, xp, cc + 1, r0, act);
        hcomp<REV>(A1, A2, A3, Ax, h0, h1, h2, h3, op, cc, r0, act, lane);
        if (cc + 2 < 56)
            hload<REV>(A1, A2, A3, Ax, g1, g2, g3, xp, cc + 2, r0, act);
        hcomp<REV>(B1, B2, B3, Bx, h0, h1, h2, h3, op, cc + 1, r0, act, lane);
    }
}

__global__ __launch_bounds__(64) void scan_kernel(const float* __restrict__ gates,
                                                  const float* __restrict__ x,
                                                  float* __restrict__ D)
{
    int bid = blockIdx.x;
    int d = bid & 3;
    int p = bid >> 2;
    int b = p >> 5;
    int c = p & 31;
    int lane = threadIdx.x;

    const float* g1 = gates + (size_t)(b * 384 + 3 * d * 32 + c) * HW2;
    const float* g2 = g1 + 32 * (size_t)HW2;
    const float* g3 = g2 + 32 * (size_t)HW2;
    const float* xp = x + (size_t)p * HW2;
    float* op = D + (size_t)d * NPLANE + (size_t)p * HW2;

    if (d == 0)      scan_h<false>(g1, g2, g3, xp, op, lane);
    else if (d == 1) scan_v<true >(g1, g2, g3, xp, op, lane);
    else if (d == 2) scan_v<false>(g1, g2, g3, xp, op, lane);
    else             scan_h<true >(g1, g2, g3, xp, op, lane);
}

__global__ __launch_bounds__(256) void max4_kernel(const float* __restrict__ D,
                                                   float* __restrict__ o)
{
    const int NP4 = NPLANE / 4;
    int idx = blockIdx.x * 256 + threadIdx.x;
    if (idx >= NP4) return;
    const f4* d0 = (const f4*)D;
    const f4* d1 = d0 + NP4;
    const f4* d2 = d1 + NP4;
    const f4* d3 = d2 + NP4;
    f4 a = d0[idx], b = d1[idx], c = d2[idx], d = d3[idx];
    f4 r;
    r.x = fmaxf(fmaxf(a.x, b.x), fmaxf(c.x, d.x));
    r.y = fmaxf(fmaxf(a.y, b.y), fmaxf(c.y, d.y));
    r.z = fmaxf(fmaxf(a.z, b.z), fmaxf(c.z, d.z));
    r.w = fmaxf(fmaxf(a.w, b.w), fmaxf(c.w, d.w));
    ((f4*)o)[idx] = r;
}

// ---------------------------------------------------------------------------
// conv_end_4 (32->2, 3x3 same) fused with log_softmax over the 2 channels
// ---------------------------------------------------------------------------
__global__ __launch_bounds__(256) void conv4ls_kernel(const float* __restrict__ x,
                                                      const float* __restrict__ w4,
                                                      float* __restrict__ out)
{
    __shared__ float wsh[576];
    for (int i = threadIdx.x; i < 576; i += 256) wsh[i] = w4[i];
    __syncthreads();
    int idx = blockIdx.x * 256 + threadIdx.x;
    if (idx >= 4 * HW2) return;
    int w = idx % 224;
    int h = (idx / 224) % 224;
    int b = idx / HW2;
    const float* xb = x + (size_t)b * 32 * HW2;
    float acc0 = 0.f, acc1 = 0.f;
    for (int ci = 0; ci < 32; ci++) {
        const float* xc = xb + ci * HW2;
#pragma unroll
        for (int kh = 0; kh < 3; kh++) {
            int hy = h + kh - 1;
            if (hy < 0 || hy > 223) continue;
#pragma unroll
            for (int kw = 0; kw < 3; kw++) {
                int wy = w + kw - 1;
                if (wy < 0 || wy > 223) continue;
                float v = xc[hy * 224 + wy];
                acc0 += v * wsh[(ci * 3 + kh) * 3 + kw];
                acc1 += v * wsh[288 + (ci * 3 + kh) * 3 + kw];
            }
        }
    }
    float m = fmaxf(acc0, acc1);
    float l = m + logf(expf(acc0 - m) + expf(acc1 - m));
    out[(size_t)(b * 2) * HW2 + h * 224 + w]     = acc0 - l;
    out[(size_t)(b * 2 + 1) * HW2 + h * 224 + w] = acc1 - l;
}

// ---------------------------------------------------------------------------
extern "C" void kernel_launch(void* const* d_in, const int* in_sizes, int n_in,
                              void* d_out, int out_size, void* d_ws, size_t ws_size,
                              hipStream_t stream)
{
    const float* gates = (const float*)d_in[0];  // [4,384,224,224]
    const float* y     = (const float*)d_in[1];  // [4,2,224,224]
    const float* w3    = (const float*)d_in[2];  // [32,2,3,3]
    const float* w4    = (const float*)d_in[3];  // [2,32,3,3]
    float* out = (float*)d_out;                  // [4,2,224,224]
    float* ws  = (float*)d_ws;

    float* x = ws;                    // NPLANE f32 (y32 -> y1 -> y2)
    float* D = ws + NPLANE;           // 4*NPLANE f32

    conv3_kernel<<<NPLANE / 256, 256, 0, stream>>>(y, w3, x);

    if (ws_size >= WS_NEED) {
        _Float16* GT = (_Float16*)(ws + (size_t)NPLANE * 5);
        packT_kernel<<<6 * 128 * 49, dim3(32, 8), 0, stream>>>(gates, GT);
        scanP_kernel<<<512, 64, 0, stream>>>(gates, GT, x, D);
        max4T_kernel<<<128 * 49, dim3(32, 8), 0, stream>>>(D, x);
        scanP_kernel<<<512, 64, 0, stream>>>(gates, GT, x, D);
        max4T_kernel<<<128 * 49, dim3(32, 8), 0, stream>>>(D, x);
    } else {
        scan_kernel<<<512, 64, 0, stream>>>(gates, x, D);
        max4_kernel<<<NPLANE / 4 / 256, 256, 0, stream>>>(D, x);
        scan_kernel<<<512, 64, 0, stream>>>(gates, x, D);
        max4_kernel<<<NPLANE / 4 / 256, 256, 0, stream>>>(D, x);
    }
    conv4ls_kernel<<<(4 * HW2) / 256, 256, 0, stream>>>(x, w4, out);
}